// Round 12
// baseline (361.908 us; speedup 1.0000x reference)
//
#include <hip/hip_runtime.h>

// RGATConv x2 (N=50000, E=800000, IN=HID=128, R=8) for MI355X/gfx950.
//
// Round-20: overlap agg(g0) with gemm(g1) — they are data-independent
// (agg0 reads xt0/sq0/sk0/csr; gemm1 writes xt1/sq1/sk1). One fused
// dispatch k_aggemm: blocks [0,2gx) = gemm(g1) (first: long blocks grab
// CUs early), rest = agg(g0). xt1 ALIASES staged (dead after scatter3);
// peak live 226.5MB — host-side ws check falls back to the verified
// round-19 5-kernel sequence if short. Serial cost 52+55=107us -> fused
// ~75-85 (shared HBM at ~4TB/s combined; L3-thrash bound ~9% per r16).
// prep/sortgemm/scatter3/agg kernels byte-identical to round-19.

typedef unsigned short u16;
typedef __attribute__((ext_vector_type(8))) short short8;
typedef __attribute__((ext_vector_type(4))) float floatx4;
typedef __attribute__((ext_vector_type(4))) float float4v;
typedef __attribute__((ext_vector_type(4))) unsigned uint4v;

#define BCAP 8192  // slots per 256-node bucket (mean 4096, sigma 64)

__device__ __forceinline__ u16 f2bf(float f) {
  union { float f; unsigned u; } v; v.f = f;
  unsigned r = v.u + 0x7FFFu + ((v.u >> 16) & 1u);  // RNE
  return (u16)(r >> 16);
}
__device__ __forceinline__ float bflo(unsigned v) {
  union { unsigned u; float f; } c; c.u = v << 16; return c.f;
}
__device__ __forceinline__ float bfhi(unsigned v) {
  union { unsigned u; float f; } c; c.u = v & 0xffff0000u; return c.f;
}
__device__ __forceinline__ unsigned cvtpk(float lo, float hi) {
  unsigned r;
  asm("v_cvt_pk_bf16_f32 %0, %1, %2" : "=v"(r) : "v"(lo), "v"(hi));
  return r;
}

// ---- 1. merged prep: Wb fragments + Bqk direct + bcnt zero ------------------
__global__ void __launch_bounds__(256) k_prep(
    const float* __restrict__ W1, const float* __restrict__ q1,
    const float* __restrict__ k1, const float* __restrict__ W2,
    const float* __restrict__ q2, const float* __restrict__ k2,
    u16* __restrict__ Wb, u16* __restrict__ Bqk, int* __restrict__ bcnt,
    int KK, int wbHalf) {
  int b = blockIdx.x, tid = threadIdx.x;
  int wbBlocks = 2 * wbHalf;
  if (b < wbBlocks) {
    int gy = b >= wbHalf;
    int t = (b - gy * wbHalf) * 256 + tid;
    int lane = t & 63, nt = (t >> 6) & 7, kk = t >> 9;
    if (kk >= KK) return;
    const float* W = gy ? W2 : W1;
    u16* out = Wb + (size_t)gy * KK * 4096;
    int q = lane >> 4, m16 = lane & 15;
    int c = nt * 16 + m16;
    short8 v;
#pragma unroll
    for (int j = 0; j < 8; ++j) {
      int k = kk * 32 + q * 8 + j;
      v[j] = (short)f2bf(W[(size_t)k * 128 + c]);
    }
    *(short8*)(out + (size_t)t * 8) = v;
  } else {
    int bb = b - wbBlocks;  // 0..15
    if (bb < 2) {
      int z = bb * 256 + tid;
      bcnt[z] = 0;
    }
    int idx = bb * 256 + tid;  // 4096 total
    int j = idx & 7, lane = (idx >> 3) & 63, kk = (idx >> 9) & 3, g = idx >> 11;
    int k = kk * 32 + ((lane >> 4) & 3) * 8 + j;
    int n = lane & 15;
    const float* W = g ? W2 : W1;
    const float* vec = (n < 8) ? (g ? q2 : q1) : (g ? k2 : k1);
    const float* row = W + ((size_t)(n & 7) * 128 + k) * 128;
    float s = 0.f;
#pragma unroll
    for (int o = 0; o < 128; o += 4) {
      float4v wv = *(const float4v*)(row + o);
      float4v qv = *(const float4v*)(vec + o);
      s += wv.x * qv.x + wv.y * qv.y + wv.z * qv.z + wv.w * qv.w;
    }
    Bqk[idx] = f2bf(s);
  }
}

// ---- shared-mem union for the fused sort+gemm kernel ------------------------
struct BinSmem {
  int hist[512];
  int basev[512];
  int runstart[512];
  unsigned sta[8192];  // 32 KB
};
union SortGemmSmem {
  BinSmem bn;
  u16 st[4][2][2048];  // gemm staging: 4 waves x 2 buffers x 4KB
};

// ---- gemm body (shared by k_sortgemm / k_gemm_xt / k_aggemm) ----------------
__device__ __forceinline__ void gemm_body(
    u16 st[4][2][2048], int bx, int by, int tid,
    const float* __restrict__ x, const u16* __restrict__ Wb,
    const u16* __restrict__ Bqk, u16* __restrict__ xt,
    float* __restrict__ sq, float* __restrict__ sk,
    int N, int node_base) {
  int wave = tid >> 6, lane = tid & 63;
  int m0 = bx * 64 + wave * 16;
  int rbase = by * 4;
  int q = lane >> 4, m16 = lane & 15;
  int node = m0 + m16;
  int srow = (node < N) ? node : N - 1;
  short8 bfrag[4];
#pragma unroll
  for (int kk = 0; kk < 4; ++kk) {
    const float* ap = x + (size_t)srow * 128 + kk * 32 + q * 8;
    float4v f0 = *(const float4v*)ap;
    float4v f1 = *(const float4v*)(ap + 4);
    union { unsigned u[4]; short8 s; } pb;
    pb.u[0] = cvtpk(f0.x, f0.y); pb.u[1] = cvtpk(f0.z, f0.w);
    pb.u[2] = cvtpk(f1.x, f1.y); pb.u[3] = cvtpk(f1.z, f1.w);
    bfrag[kk] = pb.s;
  }
  if (by == 0) {
    floatx4 accq = (floatx4){0.f, 0.f, 0.f, 0.f};
#pragma unroll
    for (int kk = 0; kk < 4; ++kk) {
      short8 aq = *(const short8*)(Bqk + (size_t)kk * 512 + lane * 8);
      accq = __builtin_amdgcn_mfma_f32_16x16x32_bf16(aq, bfrag[kk], accq, 0, 0, 0);
    }
    if (node < N) {
      float* dst = (q < 2 ? sq : sk) + (size_t)(node_base + node) * 8 + (q & 1) * 4;
      *(float4v*)dst = (float4v){accq[0], accq[1], accq[2], accq[3]};
    }
  }
#pragma unroll
  for (int rr = 0; rr < 4; ++rr) {
    int r = rbase + rr;
    u16* s = st[tid >> 6][rr & 1];
    floatx4 acc[8];
#pragma unroll
    for (int nt = 0; nt < 8; ++nt) acc[nt] = (floatx4){0.f, 0.f, 0.f, 0.f};
#pragma unroll
    for (int kk = 0; kk < 4; ++kk) {
      const u16* wbp = Wb + ((size_t)((r * 4 + kk) * 8) * 64 + lane) * 8;
#pragma unroll
      for (int nt = 0; nt < 8; ++nt) {
        short8 a = *(const short8*)(wbp + nt * 512);
        acc[nt] = __builtin_amdgcn_mfma_f32_16x16x32_bf16(a, bfrag[kk], acc[nt], 0, 0, 0);
      }
    }
#pragma unroll
    for (int nt = 0; nt < 8; ++nt) {
      union { unsigned u[2]; unsigned long long ull; } pk;
      pk.u[0] = cvtpk(acc[nt][0], acc[nt][1]);
      pk.u[1] = cvtpk(acc[nt][2], acc[nt][3]);
      int c16 = 2 * nt + (q >> 1);
      *(unsigned long long*)(s + (((m16 << 4) + (c16 ^ m16)) << 3) + ((q & 1) << 2)) = pk.ull;
    }
#pragma unroll
    for (int it = 0; it < 4; ++it) {
      int rl = it * 4 + q;
      int gm = m0 + rl;
      if (gm < N) {
        uint4v vv = *(const uint4v*)(s + (((rl << 4) + (m16 ^ rl)) << 3));
        *(uint4v*)(xt + ((size_t)r * N + gm) * 128 + m16 * 8) = vv;
      }
    }
  }
}

// ---- agg body (shared by k_aggregate / k_aggemm) ----------------------------
__device__ __forceinline__ void agg_body(
    int nl, int lane,
    const int* __restrict__ csr, const int* __restrict__ offs,
    const int* __restrict__ ends,
    const float* __restrict__ sq, const float* __restrict__ sk,
    const u16* __restrict__ xt, const float* __restrict__ bias,
    float* __restrict__ out, int N, int node_base) {
  int node = node_base + nl;
  int start = offs[node], end = ends[node];
  const float* sqn = sq + (size_t)node * 8;

  float al[8]; int pl[8];
  float m = -INFINITY;
  {
    int c = 0;
    for (int i = start + lane; i < end; i += 64, ++c) {
      int p = csr[i]; int s = p >> 3, e = p & 7;
      float a = sqn[e] + sk[(size_t)(node_base + s) * 8 + e];
      a = (a > 0.f) ? a : 0.2f * a;
      if (c < 8) { al[c] = a; pl[c] = p; }
      m = fmaxf(m, a);
    }
  }
#pragma unroll
  for (int off = 32; off; off >>= 1) m = fmaxf(m, __shfl_xor(m, off));

  float ssum = 0.f;
  {
    int c = 0;
    for (int i = start + lane; i < end; i += 64, ++c) {
      float a;
      if (c < 8) a = al[c];
      else {
        int p = csr[i]; int s = p >> 3, e = p & 7;
        a = sqn[e] + sk[(size_t)(node_base + s) * 8 + e];
        a = (a > 0.f) ? a : 0.2f * a;
      }
      ssum += __expf(a - m);
    }
  }
#pragma unroll
  for (int off = 32; off; off >>= 1) ssum += __shfl_xor(ssum, off);
  float inv = 1.f / (ssum + 1e-16f);

  float acc0 = 0.f, acc1 = 0.f;
  const char* xtb = (const char*)xt;
  int c = 0;
  for (int base = start; base < end; base += 64, ++c) {
    int cnt = min(64, end - base);
    float w = 0.f; int b = 0;
    {
      int i = base + lane;
      if (i < end) {
        int p; float a;
        if (c < 8) { p = pl[c]; a = al[c]; }
        else {
          p = csr[i]; int s = p >> 3, e = p & 7;
          a = sqn[e] + sk[(size_t)(node_base + s) * 8 + e];
          a = (a > 0.f) ? a : 0.2f * a;
        }
        w = __expf(a - m) * inv;
        b = ((p & 7) * N + (p >> 3)) << 8;  // xt row base in BYTES
      }
    }
    int j = 0;
    for (; j + 3 < cnt; j += 4) {
      float w0 = __shfl(w, j), w1 = __shfl(w, j + 1),
            w2 = __shfl(w, j + 2), w3 = __shfl(w, j + 3);
      int b0 = __shfl(b, j), b1 = __shfl(b, j + 1),
          b2 = __shfl(b, j + 2), b3 = __shfl(b, j + 3);
      unsigned v0 = *(const unsigned*)(xtb + b0 + lane * 4);
      unsigned v1 = *(const unsigned*)(xtb + b1 + lane * 4);
      unsigned v2 = *(const unsigned*)(xtb + b2 + lane * 4);
      unsigned v3 = *(const unsigned*)(xtb + b3 + lane * 4);
      acc0 += w0 * bflo(v0); acc1 += w0 * bfhi(v0);
      acc0 += w1 * bflo(v1); acc1 += w1 * bfhi(v1);
      acc0 += w2 * bflo(v2); acc1 += w2 * bfhi(v2);
      acc0 += w3 * bflo(v3); acc1 += w3 * bfhi(v3);
    }
    for (; j < cnt; ++j) {
      float w0 = __shfl(w, j);
      int b0 = __shfl(b, j);
      unsigned v0 = *(const unsigned*)(xtb + b0 + lane * 4);
      acc0 += w0 * bflo(v0); acc1 += w0 * bfhi(v0);
    }
  }
  float o0 = fmaxf(acc0 + bias[lane * 2], 0.f);
  float o1 = fmaxf(acc1 + bias[lane * 2 + 1], 0.f);
  union { float f[2]; unsigned long long u; } pk;
  pk.f[0] = o0; pk.f[1] = o1;
  __builtin_nontemporal_store(pk.u,
      (unsigned long long*)(out + (size_t)nl * 128 + lane * 2));
}

// ---- 2. fused: blocks [0,nbin) = bin2; blocks [nbin, nbin+2*gx) = gemm(g=0) -
__global__ void __launch_bounds__(256) k_sortgemm(
    const int* __restrict__ ei1, const int* __restrict__ et1,
    const int* __restrict__ ei2, const int* __restrict__ et2,
    int* __restrict__ bcnt, uint2* __restrict__ staged,
    const float* __restrict__ x, const u16* __restrict__ Wb,
    const u16* __restrict__ Bqk, u16* __restrict__ xt,
    float* __restrict__ sq, float* __restrict__ sk,
    int N, int E, int NB, int R, int nbin, int gx) {
  __shared__ SortGemmSmem sm;
  int tid = threadIdx.x;

  if ((int)blockIdx.x < nbin) {
    int* hist = sm.bn.hist;
    int* basev = sm.bn.basev;
    int* runstart = sm.bn.runstart;
    unsigned* sta = sm.bn.sta;
    int E2 = 2 * E;
    int e0 = blockIdx.x * 4096;
    int cnt2 = min(4096, E2 - e0);
    for (int i = tid; i < 512; i += 256) hist[i] = 0;
    __syncthreads();
    int dstg[16], srcet[16], rank[16];
#pragma unroll
    for (int j = 0; j < 16; ++j) {
      int e = e0 + j * 256 + tid;
      dstg[j] = -1;
      if (e < E2) {
        int g = e >= E;
        int el = e - (g ? E : 0);
        const int* ei = g ? ei2 : ei1;
        int s = ei[el], d = ei[E + el];
        int etv = (g ? et2 : et1)[el];
        dstg[j] = g * N + d;
        srcet[j] = (s << 3) | etv;
        rank[j] = atomicAdd(&hist[dstg[j] >> 8], 1);
      }
    }
    __syncthreads();
    basev[tid] = hist[tid];
    basev[tid + 256] = hist[tid + 256];
    __syncthreads();
    for (int off = 1; off < 512; off <<= 1) {
      int i0 = tid, i1 = tid + 256;
      int v0 = (i0 >= off) ? basev[i0 - off] : 0;
      int v1 = (i1 >= off) ? basev[i1 - off] : 0;
      __syncthreads();
      basev[i0] += v0; basev[i1] += v1;
      __syncthreads();
    }
    for (int i = tid; i < NB; i += 256)
      if (hist[i] > 0) runstart[i] = atomicAdd(&bcnt[i], hist[i]);
    __syncthreads();
#pragma unroll
    for (int j = 0; j < 16; ++j)
      if (dstg[j] >= 0) {
        int b = dstg[j] >> 8;
        int slot = basev[b] - hist[b] + rank[j];
        sta[slot * 2] = (unsigned)dstg[j];
        sta[slot * 2 + 1] = (unsigned)srcet[j];
      }
    __syncthreads();
    for (int i = tid; i < cnt2; i += 256) {
      unsigned dg = sta[i * 2], se = sta[i * 2 + 1];
      int b = (int)(dg >> 8);
      int dest = (b << 13) + runstart[b] + (i - (basev[b] - hist[b]));
      staged[dest] = make_uint2(dg, se);
    }
    return;
  }
  int f = blockIdx.x - nbin;
  gemm_body(sm.st, f % gx, f / gx, tid, x, Wb, Bqk, xt, sq, sk, N, 0);
}

// ---- 3. per-bucket: node-level offs/ends + sorted csr (padded space) --------
__global__ void __launch_bounds__(256) k_scatter3(
    const uint2* __restrict__ staged, const int* __restrict__ bcnt,
    int* __restrict__ offs, int* __restrict__ ends, int* __restrict__ csr,
    int N2) {
  __shared__ int hist[256];
  __shared__ int sd[256];
  __shared__ int cur[256];
  int b = blockIdx.x, tid = threadIdx.x;
  int nb0 = b << 8;
  int nnode = min(256, N2 - nb0);
  int s0 = b << 13;
  int cnt = bcnt[b];
  hist[tid] = 0;
  __syncthreads();
  for (int i = tid; i < cnt; i += 256)
    atomicAdd(&hist[(int)staged[s0 + i].x - nb0], 1);
  __syncthreads();
  int v = hist[tid];
  sd[tid] = v; __syncthreads();
  for (int off = 1; off < 256; off <<= 1) {
    int t = (tid >= off) ? sd[tid - off] : 0;
    __syncthreads();
    sd[tid] += t;
    __syncthreads();
  }
  int ex = sd[tid] - v;  // exclusive scan
  if (tid < nnode) {
    offs[nb0 + tid] = s0 + ex;
    ends[nb0 + tid] = s0 + ex + v;
  }
  cur[tid] = ex;
  __syncthreads();
  for (int i = tid; i < cnt; i += 256) {
    uint2 en = staged[s0 + i];
    int node = (int)en.x - nb0;
    int sl = atomicAdd(&cur[node], 1);
    csr[s0 + sl] = (int)en.y;
  }
}

// ---- 4. fused agg(g0) + gemm(g1): blocks [0,2gx) gemm, rest agg -------------
__global__ void __launch_bounds__(256) k_aggemm(
    const int* __restrict__ csr, const int* __restrict__ offs,
    const int* __restrict__ ends,
    const float* __restrict__ sq, const float* __restrict__ sk,
    const u16* __restrict__ xt0, const float* __restrict__ b1,
    float* __restrict__ out,
    const float* __restrict__ x2, const u16* __restrict__ Wb1,
    const u16* __restrict__ Bqk1, u16* __restrict__ xt1,
    float* __restrict__ sqw, float* __restrict__ skw,
    int N, int R, int gx) {
  __shared__ u16 st[4][2][2048];
  int tid = threadIdx.x;
  if ((int)blockIdx.x < 2 * gx) {
    int f = blockIdx.x;
    gemm_body(st, f % gx, f / gx, tid, x2, Wb1, Bqk1, xt1, sqw, skw, N, N);
    return;
  }
  int nl = (blockIdx.x - 2 * gx) * 4 + (tid >> 6);
  if (nl >= N) return;
  agg_body(nl, tid & 63, csr, offs, ends, sq, sk, xt0, b1, out, N, 0);
}

// ---- 5. standalone gemm (fallback g=1) --------------------------------------
__global__ void __launch_bounds__(256) k_gemm_xt(
    const float* __restrict__ x, const u16* __restrict__ Wb,
    const u16* __restrict__ Bqk, u16* __restrict__ xt,
    float* __restrict__ sq, float* __restrict__ sk,
    int N, int R, int node_base) {
  __shared__ u16 st[4][2][2048];
  gemm_body(st, blockIdx.x, blockIdx.y, threadIdx.x, x, Wb, Bqk, xt, sq, sk,
            N, node_base);
}

// ---- 6. standalone aggregate ------------------------------------------------
__global__ void __launch_bounds__(256) k_aggregate(
    const int* __restrict__ csr, const int* __restrict__ offs,
    const int* __restrict__ ends,
    const float* __restrict__ sq, const float* __restrict__ sk,
    const u16* __restrict__ xt, const float* __restrict__ bias,
    float* __restrict__ out, int N, int node_base) {
  int nl = blockIdx.x * 4 + (threadIdx.x >> 6);
  if (nl >= N) return;
  agg_body(nl, threadIdx.x & 63, csr, offs, ends, sq, sk, xt, bias, out, N,
           node_base);
}

// -----------------------------------------------------------------------------
extern "C" void kernel_launch(void* const* d_in, const int* in_sizes, int n_in,
                              void* d_out, int out_size, void* d_ws, size_t ws_size,
                              hipStream_t stream) {
  const float* x1 = (const float*)d_in[0];
  const int* ei1 = (const int*)d_in[1];
  const int* et1 = (const int*)d_in[2];
  const float* x2 = (const float*)d_in[3];
  const int* ei2 = (const int*)d_in[4];
  const int* et2 = (const int*)d_in[5];
  const float* W1 = (const float*)d_in[6];
  const float* q1 = (const float*)d_in[7];
  const float* k1 = (const float*)d_in[8];
  const float* b1 = (const float*)d_in[9];
  const float* W2 = (const float*)d_in[10];
  const float* q2 = (const float*)d_in[11];
  const float* k2 = (const float*)d_in[12];
  const float* b2 = (const float*)d_in[13];

  const int N = in_sizes[0] / 128;
  const int E = in_sizes[1] / 2;
  const int R = in_sizes[6] / (128 * 128);
  const int KK = R * 4;
  const int N2 = 2 * N;
  const int NB = (N2 + 255) >> 8;           // 256-node buckets (<=512)

  size_t off = 0;
  char* w = (char*)d_ws;
  auto carve = [&](size_t bytes) -> void* {
    void* p = w + off;
    off += (bytes + 255) & ~(size_t)255;
    return p;
  };
  u16* Wb = (u16*)carve((size_t)2 * KK * 4096 * 2);
  u16* Bqk = (u16*)carve((size_t)2 * 4 * 64 * 8 * 2);
  float* sq = (float*)carve((size_t)N2 * 8 * 4);
  float* sk = (float*)carve((size_t)N2 * 8 * 4);
  int* offs = (int*)carve((size_t)N2 * 4);
  int* ends = (int*)carve((size_t)N2 * 4);
  int* bcnt = (int*)carve(512 * 4);
  int* csr = (int*)carve((size_t)NB * BCAP * 4);
  u16* xt0 = (u16*)carve((size_t)R * N * 128 * 2);
  size_t staged_off = off;
  uint2* staged = (uint2*)carve((size_t)NB * BCAP * 8);
  if (off > ws_size) return;
  // dual-xt mode: xt1 aliases staged (dead after scatter3), extends past it
  size_t xt_bytes = (size_t)R * N * 128 * 2;
  bool dual = (staged_off + xt_bytes) <= ws_size;
  u16* xt1 = dual ? (u16*)(w + staged_off) : xt0;

  const int nbin = (2 * E + 4095) / 4096;
  const int gx = (N + 63) / 64;
  const int wbHalf = (KK * 512 + 255) / 256;
  const int na = (N + 3) / 4;

  k_prep<<<dim3(2 * wbHalf + 16), dim3(256), 0, stream>>>(
      W1, q1, k1, W2, q2, k2, Wb, Bqk, bcnt, KK, wbHalf);
  k_sortgemm<<<dim3(nbin + 2 * gx), dim3(256), 0, stream>>>(
      ei1, et1, ei2, et2, bcnt, staged,
      x1, Wb, Bqk, xt0, sq, sk, N, E, NB, R, nbin, gx);
  k_scatter3<<<dim3(NB), dim3(256), 0, stream>>>(staged, bcnt, offs, ends, csr, N2);

  if (dual) {
    k_aggemm<<<dim3(2 * gx + na), dim3(256), 0, stream>>>(
        csr, offs, ends, sq, sk, xt0, b1, (float*)d_out,
        x2, Wb + (size_t)KK * 4096, Bqk + 2048, xt1, sq, sk, N, R, gx);
    k_aggregate<<<dim3(na), dim3(256), 0, stream>>>(
        csr, offs, ends, sq, sk, xt1, b2,
        (float*)d_out + (size_t)N * 128, N, N);
  } else {
    k_aggregate<<<dim3(na), dim3(256), 0, stream>>>(
        csr, offs, ends, sq, sk, xt0, b1, (float*)d_out, N, 0);
    k_gemm_xt<<<dim3(gx, 2), dim3(256), 0, stream>>>(
        x2, Wb + (size_t)KK * 4096, Bqk + 2048, xt0, sq, sk, N, R, N);
    k_aggregate<<<dim3(na), dim3(256), 0, stream>>>(
        csr, offs, ends, sq, sk, xt0, b2,
        (float*)d_out + (size_t)N * 128, N, N);
  }
}

// Round 13
// 338.483 us; speedup vs baseline: 1.0692x; 1.0692x over previous
//
#include <hip/hip_runtime.h>

// RGATConv x2 (N=50000, E=800000, IN=HID=128, R=8) for MI355X/gfx950.
//
// Round-21: schedule restructure on the dependency graph, dual xt buffers
// (NO staged alias; ~251MB, runtime-checked, fallback = verified round-19).
//   1 prep
//   2 k_sortgemm2: bin2 || gemm(g0)->xt0 || gemm(g1)->xt1  (all independent,
//     all LDS-heavy -> homogeneous fusion, the pattern that worked in r19;
//     single gemm is issue-bound at 33% fabric so two should scale)
//   3 scatter3
//   4 k_agg2: merged agg, both graphs (0 LDS / 28 VGPR / 78% occ profile —
//     r16 measured 109us for this exact shape)
// Round-20 lesson: heterogeneous fusion makes agg inherit gemm's 32KB LDS
// -> occupancy 78->40% and +19us; never fuse latency-bound low-resource
// blocks into high-LDS kernels.

typedef unsigned short u16;
typedef __attribute__((ext_vector_type(8))) short short8;
typedef __attribute__((ext_vector_type(4))) float floatx4;
typedef __attribute__((ext_vector_type(4))) float float4v;
typedef __attribute__((ext_vector_type(4))) unsigned uint4v;

#define BCAP 8192  // slots per 256-node bucket (mean 4096, sigma 64)

__device__ __forceinline__ u16 f2bf(float f) {
  union { float f; unsigned u; } v; v.f = f;
  unsigned r = v.u + 0x7FFFu + ((v.u >> 16) & 1u);  // RNE
  return (u16)(r >> 16);
}
__device__ __forceinline__ float bflo(unsigned v) {
  union { unsigned u; float f; } c; c.u = v << 16; return c.f;
}
__device__ __forceinline__ float bfhi(unsigned v) {
  union { unsigned u; float f; } c; c.u = v & 0xffff0000u; return c.f;
}
__device__ __forceinline__ unsigned cvtpk(float lo, float hi) {
  unsigned r;
  asm("v_cvt_pk_bf16_f32 %0, %1, %2" : "=v"(r) : "v"(lo), "v"(hi));
  return r;
}

// ---- 1. merged prep: Wb fragments + Bqk direct + bcnt zero ------------------
__global__ void __launch_bounds__(256) k_prep(
    const float* __restrict__ W1, const float* __restrict__ q1,
    const float* __restrict__ k1, const float* __restrict__ W2,
    const float* __restrict__ q2, const float* __restrict__ k2,
    u16* __restrict__ Wb, u16* __restrict__ Bqk, int* __restrict__ bcnt,
    int KK, int wbHalf) {
  int b = blockIdx.x, tid = threadIdx.x;
  int wbBlocks = 2 * wbHalf;
  if (b < wbBlocks) {
    int gy = b >= wbHalf;
    int t = (b - gy * wbHalf) * 256 + tid;
    int lane = t & 63, nt = (t >> 6) & 7, kk = t >> 9;
    if (kk >= KK) return;
    const float* W = gy ? W2 : W1;
    u16* out = Wb + (size_t)gy * KK * 4096;
    int q = lane >> 4, m16 = lane & 15;
    int c = nt * 16 + m16;
    short8 v;
#pragma unroll
    for (int j = 0; j < 8; ++j) {
      int k = kk * 32 + q * 8 + j;
      v[j] = (short)f2bf(W[(size_t)k * 128 + c]);
    }
    *(short8*)(out + (size_t)t * 8) = v;
  } else {
    int bb = b - wbBlocks;  // 0..15
    if (bb < 2) {
      int z = bb * 256 + tid;
      bcnt[z] = 0;
    }
    int idx = bb * 256 + tid;  // 4096 total
    int j = idx & 7, lane = (idx >> 3) & 63, kk = (idx >> 9) & 3, g = idx >> 11;
    int k = kk * 32 + ((lane >> 4) & 3) * 8 + j;
    int n = lane & 15;
    const float* W = g ? W2 : W1;
    const float* vec = (n < 8) ? (g ? q2 : q1) : (g ? k2 : k1);
    const float* row = W + ((size_t)(n & 7) * 128 + k) * 128;
    float s = 0.f;
#pragma unroll
    for (int o = 0; o < 128; o += 4) {
      float4v wv = *(const float4v*)(row + o);
      float4v qv = *(const float4v*)(vec + o);
      s += wv.x * qv.x + wv.y * qv.y + wv.z * qv.z + wv.w * qv.w;
    }
    Bqk[idx] = f2bf(s);
  }
}

// ---- shared-mem union for the fused sort+gemm kernel ------------------------
struct BinSmem {
  int hist[512];
  int basev[512];
  int runstart[512];
  unsigned sta[8192];  // 32 KB
};
union SortGemmSmem {
  BinSmem bn;
  u16 st[4][2][2048];  // gemm staging: 4 waves x 2 buffers x 4KB
};

// ---- gemm body --------------------------------------------------------------
__device__ __forceinline__ void gemm_body(
    u16 st[4][2][2048], int bx, int by, int tid,
    const float* __restrict__ x, const u16* __restrict__ Wb,
    const u16* __restrict__ Bqk, u16* __restrict__ xt,
    float* __restrict__ sq, float* __restrict__ sk,
    int N, int node_base) {
  int wave = tid >> 6, lane = tid & 63;
  int m0 = bx * 64 + wave * 16;
  int rbase = by * 4;
  int q = lane >> 4, m16 = lane & 15;
  int node = m0 + m16;
  int srow = (node < N) ? node : N - 1;
  short8 bfrag[4];
#pragma unroll
  for (int kk = 0; kk < 4; ++kk) {
    const float* ap = x + (size_t)srow * 128 + kk * 32 + q * 8;
    float4v f0 = *(const float4v*)ap;
    float4v f1 = *(const float4v*)(ap + 4);
    union { unsigned u[4]; short8 s; } pb;
    pb.u[0] = cvtpk(f0.x, f0.y); pb.u[1] = cvtpk(f0.z, f0.w);
    pb.u[2] = cvtpk(f1.x, f1.y); pb.u[3] = cvtpk(f1.z, f1.w);
    bfrag[kk] = pb.s;
  }
  if (by == 0) {
    floatx4 accq = (floatx4){0.f, 0.f, 0.f, 0.f};
#pragma unroll
    for (int kk = 0; kk < 4; ++kk) {
      short8 aq = *(const short8*)(Bqk + (size_t)kk * 512 + lane * 8);
      accq = __builtin_amdgcn_mfma_f32_16x16x32_bf16(aq, bfrag[kk], accq, 0, 0, 0);
    }
    if (node < N) {
      float* dst = (q < 2 ? sq : sk) + (size_t)(node_base + node) * 8 + (q & 1) * 4;
      *(float4v*)dst = (float4v){accq[0], accq[1], accq[2], accq[3]};
    }
  }
#pragma unroll
  for (int rr = 0; rr < 4; ++rr) {
    int r = rbase + rr;
    u16* s = st[tid >> 6][rr & 1];
    floatx4 acc[8];
#pragma unroll
    for (int nt = 0; nt < 8; ++nt) acc[nt] = (floatx4){0.f, 0.f, 0.f, 0.f};
#pragma unroll
    for (int kk = 0; kk < 4; ++kk) {
      const u16* wbp = Wb + ((size_t)((r * 4 + kk) * 8) * 64 + lane) * 8;
#pragma unroll
      for (int nt = 0; nt < 8; ++nt) {
        short8 a = *(const short8*)(wbp + nt * 512);
        acc[nt] = __builtin_amdgcn_mfma_f32_16x16x32_bf16(a, bfrag[kk], acc[nt], 0, 0, 0);
      }
    }
#pragma unroll
    for (int nt = 0; nt < 8; ++nt) {
      union { unsigned u[2]; unsigned long long ull; } pk;
      pk.u[0] = cvtpk(acc[nt][0], acc[nt][1]);
      pk.u[1] = cvtpk(acc[nt][2], acc[nt][3]);
      int c16 = 2 * nt + (q >> 1);
      *(unsigned long long*)(s + (((m16 << 4) + (c16 ^ m16)) << 3) + ((q & 1) << 2)) = pk.ull;
    }
#pragma unroll
    for (int it = 0; it < 4; ++it) {
      int rl = it * 4 + q;
      int gm = m0 + rl;
      if (gm < N) {
        uint4v vv = *(const uint4v*)(s + (((rl << 4) + (m16 ^ rl)) << 3));
        *(uint4v*)(xt + ((size_t)r * N + gm) * 128 + m16 * 8) = vv;
      }
    }
  }
}

// ---- agg body ---------------------------------------------------------------
__device__ __forceinline__ void agg_body(
    int nl, int lane,
    const int* __restrict__ csr, const int* __restrict__ offs,
    const int* __restrict__ ends,
    const float* __restrict__ sq, const float* __restrict__ sk,
    const u16* __restrict__ xt, const float* __restrict__ bias,
    float* __restrict__ out, int N, int node_base) {
  int node = node_base + nl;
  int start = offs[node], end = ends[node];
  const float* sqn = sq + (size_t)node * 8;

  float al[8]; int pl[8];
  float m = -INFINITY;
  {
    int c = 0;
    for (int i = start + lane; i < end; i += 64, ++c) {
      int p = csr[i]; int s = p >> 3, e = p & 7;
      float a = sqn[e] + sk[(size_t)(node_base + s) * 8 + e];
      a = (a > 0.f) ? a : 0.2f * a;
      if (c < 8) { al[c] = a; pl[c] = p; }
      m = fmaxf(m, a);
    }
  }
#pragma unroll
  for (int off = 32; off; off >>= 1) m = fmaxf(m, __shfl_xor(m, off));

  float ssum = 0.f;
  {
    int c = 0;
    for (int i = start + lane; i < end; i += 64, ++c) {
      float a;
      if (c < 8) a = al[c];
      else {
        int p = csr[i]; int s = p >> 3, e = p & 7;
        a = sqn[e] + sk[(size_t)(node_base + s) * 8 + e];
        a = (a > 0.f) ? a : 0.2f * a;
      }
      ssum += __expf(a - m);
    }
  }
#pragma unroll
  for (int off = 32; off; off >>= 1) ssum += __shfl_xor(ssum, off);
  float inv = 1.f / (ssum + 1e-16f);

  float acc0 = 0.f, acc1 = 0.f;
  const char* xtb = (const char*)xt;
  int c = 0;
  for (int base = start; base < end; base += 64, ++c) {
    int cnt = min(64, end - base);
    float w = 0.f; int b = 0;
    {
      int i = base + lane;
      if (i < end) {
        int p; float a;
        if (c < 8) { p = pl[c]; a = al[c]; }
        else {
          p = csr[i]; int s = p >> 3, e = p & 7;
          a = sqn[e] + sk[(size_t)(node_base + s) * 8 + e];
          a = (a > 0.f) ? a : 0.2f * a;
        }
        w = __expf(a - m) * inv;
        b = ((p & 7) * N + (p >> 3)) << 8;  // xt row base in BYTES
      }
    }
    int j = 0;
    for (; j + 3 < cnt; j += 4) {
      float w0 = __shfl(w, j), w1 = __shfl(w, j + 1),
            w2 = __shfl(w, j + 2), w3 = __shfl(w, j + 3);
      int b0 = __shfl(b, j), b1 = __shfl(b, j + 1),
          b2 = __shfl(b, j + 2), b3 = __shfl(b, j + 3);
      unsigned v0 = *(const unsigned*)(xtb + b0 + lane * 4);
      unsigned v1 = *(const unsigned*)(xtb + b1 + lane * 4);
      unsigned v2 = *(const unsigned*)(xtb + b2 + lane * 4);
      unsigned v3 = *(const unsigned*)(xtb + b3 + lane * 4);
      acc0 += w0 * bflo(v0); acc1 += w0 * bfhi(v0);
      acc0 += w1 * bflo(v1); acc1 += w1 * bfhi(v1);
      acc0 += w2 * bflo(v2); acc1 += w2 * bfhi(v2);
      acc0 += w3 * bflo(v3); acc1 += w3 * bfhi(v3);
    }
    for (; j < cnt; ++j) {
      float w0 = __shfl(w, j);
      int b0 = __shfl(b, j);
      unsigned v0 = *(const unsigned*)(xtb + b0 + lane * 4);
      acc0 += w0 * bflo(v0); acc1 += w0 * bfhi(v0);
    }
  }
  float o0 = fmaxf(acc0 + bias[lane * 2], 0.f);
  float o1 = fmaxf(acc1 + bias[lane * 2 + 1], 0.f);
  union { float f[2]; unsigned long long u; } pk;
  pk.f[0] = o0; pk.f[1] = o1;
  __builtin_nontemporal_store(pk.u,
      (unsigned long long*)(out + (size_t)nl * 128 + lane * 2));
}

// ---- 2. fused: bin2 || gemm(g0) || gemm(g1) ---------------------------------
// blocks [0,nbin) = bin2; [nbin, nbin+2gx) = gemm g0; [nbin+2gx, nbin+4gx) =
// gemm g1 (grid may stop at nbin+2gx in fallback mode).
__global__ void __launch_bounds__(256) k_sortgemm2(
    const int* __restrict__ ei1, const int* __restrict__ et1,
    const int* __restrict__ ei2, const int* __restrict__ et2,
    int* __restrict__ bcnt, uint2* __restrict__ staged,
    const float* __restrict__ x1, const float* __restrict__ x2,
    const u16* __restrict__ Wb, const u16* __restrict__ Bqk,
    u16* __restrict__ xt0, u16* __restrict__ xt1,
    float* __restrict__ sq, float* __restrict__ sk,
    int N, int E, int NB, int R, int nbin, int gx, int KK) {
  __shared__ SortGemmSmem sm;
  int tid = threadIdx.x;

  if ((int)blockIdx.x < nbin) {
    int* hist = sm.bn.hist;
    int* basev = sm.bn.basev;
    int* runstart = sm.bn.runstart;
    unsigned* sta = sm.bn.sta;
    int E2 = 2 * E;
    int e0 = blockIdx.x * 4096;
    int cnt2 = min(4096, E2 - e0);
    for (int i = tid; i < 512; i += 256) hist[i] = 0;
    __syncthreads();
    int dstg[16], srcet[16], rank[16];
#pragma unroll
    for (int j = 0; j < 16; ++j) {
      int e = e0 + j * 256 + tid;
      dstg[j] = -1;
      if (e < E2) {
        int g = e >= E;
        int el = e - (g ? E : 0);
        const int* ei = g ? ei2 : ei1;
        int s = ei[el], d = ei[E + el];
        int etv = (g ? et2 : et1)[el];
        dstg[j] = g * N + d;
        srcet[j] = (s << 3) | etv;
        rank[j] = atomicAdd(&hist[dstg[j] >> 8], 1);
      }
    }
    __syncthreads();
    basev[tid] = hist[tid];
    basev[tid + 256] = hist[tid + 256];
    __syncthreads();
    for (int off = 1; off < 512; off <<= 1) {
      int i0 = tid, i1 = tid + 256;
      int v0 = (i0 >= off) ? basev[i0 - off] : 0;
      int v1 = (i1 >= off) ? basev[i1 - off] : 0;
      __syncthreads();
      basev[i0] += v0; basev[i1] += v1;
      __syncthreads();
    }
    for (int i = tid; i < NB; i += 256)
      if (hist[i] > 0) runstart[i] = atomicAdd(&bcnt[i], hist[i]);
    __syncthreads();
#pragma unroll
    for (int j = 0; j < 16; ++j)
      if (dstg[j] >= 0) {
        int b = dstg[j] >> 8;
        int slot = basev[b] - hist[b] + rank[j];
        sta[slot * 2] = (unsigned)dstg[j];
        sta[slot * 2 + 1] = (unsigned)srcet[j];
      }
    __syncthreads();
    for (int i = tid; i < cnt2; i += 256) {
      unsigned dg = sta[i * 2], se = sta[i * 2 + 1];
      int b = (int)(dg >> 8);
      int dest = (b << 13) + runstart[b] + (i - (basev[b] - hist[b]));
      staged[dest] = make_uint2(dg, se);
    }
    return;
  }
  int f = blockIdx.x - nbin;
  if (f < 2 * gx) {
    gemm_body(sm.st, f % gx, f / gx, tid, x1, Wb, Bqk, xt0, sq, sk, N, 0);
  } else {
    f -= 2 * gx;
    gemm_body(sm.st, f % gx, f / gx, tid, x2, Wb + (size_t)KK * 4096,
              Bqk + 2048, xt1, sq, sk, N, N);
  }
}

// ---- 3. per-bucket: node-level offs/ends + sorted csr (padded space) --------
__global__ void __launch_bounds__(256) k_scatter3(
    const uint2* __restrict__ staged, const int* __restrict__ bcnt,
    int* __restrict__ offs, int* __restrict__ ends, int* __restrict__ csr,
    int N2) {
  __shared__ int hist[256];
  __shared__ int sd[256];
  __shared__ int cur[256];
  int b = blockIdx.x, tid = threadIdx.x;
  int nb0 = b << 8;
  int nnode = min(256, N2 - nb0);
  int s0 = b << 13;
  int cnt = bcnt[b];
  hist[tid] = 0;
  __syncthreads();
  for (int i = tid; i < cnt; i += 256)
    atomicAdd(&hist[(int)staged[s0 + i].x - nb0], 1);
  __syncthreads();
  int v = hist[tid];
  sd[tid] = v; __syncthreads();
  for (int off = 1; off < 256; off <<= 1) {
    int t = (tid >= off) ? sd[tid - off] : 0;
    __syncthreads();
    sd[tid] += t;
    __syncthreads();
  }
  int ex = sd[tid] - v;  // exclusive scan
  if (tid < nnode) {
    offs[nb0 + tid] = s0 + ex;
    ends[nb0 + tid] = s0 + ex + v;
  }
  cur[tid] = ex;
  __syncthreads();
  for (int i = tid; i < cnt; i += 256) {
    uint2 en = staged[s0 + i];
    int node = (int)en.x - nb0;
    int sl = atomicAdd(&cur[node], 1);
    csr[s0 + sl] = (int)en.y;
  }
}

// ---- 4. merged agg (both graphs; standalone resource profile) ---------------
__global__ void __launch_bounds__(256) k_agg2(
    const int* __restrict__ csr, const int* __restrict__ offs,
    const int* __restrict__ ends,
    const float* __restrict__ sq, const float* __restrict__ sk,
    const u16* __restrict__ xt0, const u16* __restrict__ xt1,
    const float* __restrict__ b1, const float* __restrict__ b2,
    float* __restrict__ out, int N, int na) {
  int g = (int)blockIdx.x >= na;
  int nl = (blockIdx.x - g * na) * 4 + (threadIdx.x >> 6);
  if (nl >= N) return;
  agg_body(nl, threadIdx.x & 63, csr, offs, ends, sq, sk,
           g ? xt1 : xt0, g ? b2 : b1,
           out + (size_t)g * N * 128, N, g * N);
}

// ---- 5. standalone gemm (fallback g=1) --------------------------------------
__global__ void __launch_bounds__(256) k_gemm_xt(
    const float* __restrict__ x, const u16* __restrict__ Wb,
    const u16* __restrict__ Bqk, u16* __restrict__ xt,
    float* __restrict__ sq, float* __restrict__ sk,
    int N, int R, int node_base) {
  __shared__ u16 st[4][2][2048];
  gemm_body(st, blockIdx.x, blockIdx.y, threadIdx.x, x, Wb, Bqk, xt, sq, sk,
            N, node_base);
}

// ---- 6. standalone aggregate (fallback) -------------------------------------
__global__ void __launch_bounds__(256) k_aggregate(
    const int* __restrict__ csr, const int* __restrict__ offs,
    const int* __restrict__ ends,
    const float* __restrict__ sq, const float* __restrict__ sk,
    const u16* __restrict__ xt, const float* __restrict__ bias,
    float* __restrict__ out, int N, int node_base) {
  int nl = blockIdx.x * 4 + (threadIdx.x >> 6);
  if (nl >= N) return;
  agg_body(nl, threadIdx.x & 63, csr, offs, ends, sq, sk, xt, bias, out, N,
           node_base);
}

// -----------------------------------------------------------------------------
extern "C" void kernel_launch(void* const* d_in, const int* in_sizes, int n_in,
                              void* d_out, int out_size, void* d_ws, size_t ws_size,
                              hipStream_t stream) {
  const float* x1 = (const float*)d_in[0];
  const int* ei1 = (const int*)d_in[1];
  const int* et1 = (const int*)d_in[2];
  const float* x2 = (const float*)d_in[3];
  const int* ei2 = (const int*)d_in[4];
  const int* et2 = (const int*)d_in[5];
  const float* W1 = (const float*)d_in[6];
  const float* q1 = (const float*)d_in[7];
  const float* k1 = (const float*)d_in[8];
  const float* b1 = (const float*)d_in[9];
  const float* W2 = (const float*)d_in[10];
  const float* q2 = (const float*)d_in[11];
  const float* k2 = (const float*)d_in[12];
  const float* b2 = (const float*)d_in[13];

  const int N = in_sizes[0] / 128;
  const int E = in_sizes[1] / 2;
  const int R = in_sizes[6] / (128 * 128);
  const int KK = R * 4;
  const int N2 = 2 * N;
  const int NB = (N2 + 255) >> 8;           // 256-node buckets (<=512)

  size_t off = 0;
  char* w = (char*)d_ws;
  auto carve = [&](size_t bytes) -> void* {
    void* p = w + off;
    off += (bytes + 255) & ~(size_t)255;
    return p;
  };
  u16* Wb = (u16*)carve((size_t)2 * KK * 4096 * 2);
  u16* Bqk = (u16*)carve((size_t)2 * 4 * 64 * 8 * 2);
  float* sq = (float*)carve((size_t)N2 * 8 * 4);
  float* sk = (float*)carve((size_t)N2 * 8 * 4);
  int* offs = (int*)carve((size_t)N2 * 4);
  int* ends = (int*)carve((size_t)N2 * 4);
  int* bcnt = (int*)carve(512 * 4);
  int* csr = (int*)carve((size_t)NB * BCAP * 4);
  u16* xt0 = (u16*)carve((size_t)R * N * 128 * 2);
  size_t staged_off = off;
  uint2* staged = (uint2*)carve((size_t)NB * BCAP * 8);
  size_t xt_bytes = (size_t)R * N * 128 * 2;
  // primary: xt1 AFTER staged (no alias) -> bin2 and gemm1 can run together
  bool tri = (off + xt_bytes) <= ws_size;
  u16* xt1 = tri ? (u16*)carve(xt_bytes)
                 : ((staged_off + xt_bytes) <= ws_size ? (u16*)(w + staged_off)
                                                       : xt0);
  if (!tri) off = staged_off + ((size_t)NB * BCAP * 8 + 255 & ~(size_t)255);
  if (off > ws_size) return;

  const int nbin = (2 * E + 4095) / 4096;
  const int gx = (N + 63) / 64;
  const int wbHalf = (KK * 512 + 255) / 256;
  const int na = (N + 3) / 4;

  k_prep<<<dim3(2 * wbHalf + 16), dim3(256), 0, stream>>>(
      W1, q1, k1, W2, q2, k2, Wb, Bqk, bcnt, KK, wbHalf);

  if (tri) {
    // 2: bin2 || gemm0 || gemm1
    k_sortgemm2<<<dim3(nbin + 4 * gx), dim3(256), 0, stream>>>(
        ei1, et1, ei2, et2, bcnt, staged, x1, x2, Wb, Bqk,
        xt0, xt1, sq, sk, N, E, NB, R, nbin, gx, KK);
    // 3: scatter
    k_scatter3<<<dim3(NB), dim3(256), 0, stream>>>(staged, bcnt, offs, ends, csr, N2);
    // 4: merged agg
    k_agg2<<<dim3(2 * na), dim3(256), 0, stream>>>(
        csr, offs, ends, sq, sk, xt0, xt1, b1, b2, (float*)d_out, N, na);
  } else {
    // fallback: exact round-19 sequence (verified 324.2us)
    k_sortgemm2<<<dim3(nbin + 2 * gx), dim3(256), 0, stream>>>(
        ei1, et1, ei2, et2, bcnt, staged, x1, x2, Wb, Bqk,
        xt0, xt1, sq, sk, N, E, NB, R, nbin, gx, KK);
    k_scatter3<<<dim3(NB), dim3(256), 0, stream>>>(staged, bcnt, offs, ends, csr, N2);
    k_aggregate<<<dim3(na), dim3(256), 0, stream>>>(
        csr, offs, ends, sq, sk, xt0, b1, (float*)d_out, N, 0);
    k_gemm_xt<<<dim3(gx, 2), dim3(256), 0, stream>>>(
        x2, Wb + (size_t)KK * 4096, Bqk + 2048, xt0, sq, sk, N, R, N);
    k_aggregate<<<dim3(na), dim3(256), 0, stream>>>(
        csr, offs, ends, sq, sk, xt0, b2,
        (float*)d_out + (size_t)N * 128, N, N);
  }
}